// Round 10
// baseline (89.849 us; speedup 1.0000x reference)
//
#include <hip/hip_runtime.h>
#include <stdint.h>

#define B_  2048
#define D_  1024
#define F_  1024
#define S_  64
#define R_  16

typedef __attribute__((ext_vector_type(8))) short  s16x8;
typedef __attribute__((ext_vector_type(4))) unsigned short u16x4;
typedef __attribute__((ext_vector_type(8))) unsigned short u16x8;
typedef __attribute__((ext_vector_type(4))) float  f32x4;

__device__ __forceinline__ unsigned short f2b(float f){
  unsigned u = __float_as_uint(f);
  u = u + 0x7fffu + ((u >> 16) & 1u);   // RNE to bf16
  return (unsigned short)(u >> 16);
}
__device__ __forceinline__ float b2f(unsigned short s){
  return __uint_as_float(((unsigned)s) << 16);
}

__device__ __forceinline__ void gload16(const void* g, void* l){
  __builtin_amdgcn_global_load_lds((const __attribute__((address_space(1))) unsigned int*)g,
                                   (__attribute__((address_space(3))) unsigned int*)l, 16, 0, 0);
}

// unit order (gemm + delta): 0=ir(x) 1=rr(c) 2=iu(x) 3=ru(c) 4=ic(x) 5=rc(c); all K=1024
// low g order: 0=ir 1=iu 2=ic 3=rr 4=ru 5=rc

// ---------------- kernel 1: fused prep = cast_xc | wcast | bucket (block-partitioned) -----
__global__ __launch_bounds__(256) void prep_kernel(
    const float* __restrict__ x, const float* __restrict__ carry,
    unsigned short* __restrict__ XC,
    const float* __restrict__ w_ir, const float* __restrict__ w_rr,
    const float* __restrict__ w_iu, const float* __restrict__ w_ru,
    const float* __restrict__ w_ic, const float* __restrict__ w_rc,
    unsigned short* __restrict__ Wt_all,
    const int* __restrict__ ids, int* __restrict__ starts, int* __restrict__ order){
  int bx = blockIdx.x;
  int t = threadIdx.x;
  if (bx < 2048){
    int i = bx * 256 + t;
    int b = i >> 8;
    int j = (i & 255) * 4;
    float4 xv = *(const float4*)&x[(size_t)b*D_ + j];
    float4 cv = *(const float4*)&carry[(size_t)b*F_ + j];
    u16x4 xs, cs;
    xs[0]=f2b(xv.x); xs[1]=f2b(xv.y); xs[2]=f2b(xv.z); xs[3]=f2b(xv.w);
    cs[0]=f2b(cv.x); cs[1]=f2b(cv.y); cs[2]=f2b(cv.z); cs[3]=f2b(cv.w);
    *(u16x4*)&XC[(size_t)b*2048 + j]        = xs;
    *(u16x4*)&XC[(size_t)b*2048 + 1024 + j] = cs;
    return;
  }
  if (bx < 3584){
    int wb = bx - 2048;
    int g = wb >> 8, xb = wb & 255;
    const float* W;
    switch(g){ case 0: W=w_ir; break; case 1: W=w_rr; break; case 2: W=w_iu; break;
               case 3: W=w_ru; break; case 4: W=w_ic; break; default: W=w_rc; break; }
    unsigned short* O = Wt_all + (size_t)g * 1048576;
    __shared__ unsigned short T[64][72];   // row stride 144B (9*16B)
    int n0 = (xb & 15) * 64;
    int k0 = (xb >> 4) * 64;
    int c4 = (t & 15) * 4;
    int kk = t >> 4;
    #pragma unroll
    for (int i = 0; i < 4; i++){
      int k = kk + i*16;
      float4 v = *(const float4*)&W[(size_t)(k0+k)*F_ + n0 + c4];
      T[c4+0][k] = f2b(v.x); T[c4+1][k] = f2b(v.y); T[c4+2][k] = f2b(v.z); T[c4+3][k] = f2b(v.w);
    }
    __syncthreads();
    int n = t >> 2, ch = (t & 3) * 16;
    u16x8 a = *(const u16x8*)&T[n][ch];
    u16x8 b = *(const u16x8*)&T[n][ch+8];
    *(u16x8*)&O[(size_t)(n0+n)*1024 + k0 + ch]     = a;
    *(u16x8*)&O[(size_t)(n0+n)*1024 + k0 + ch + 8] = b;
    return;
  }
  // bucket
  __shared__ int cnt[S_]; __shared__ int off[S_+1]; __shared__ int cur[S_];
  if (t < S_) cnt[t] = 0;
  __syncthreads();
  for (int b = t; b < B_; b += 256) atomicAdd(&cnt[ids[b]], 1);
  __syncthreads();
  if (t == 0){ off[0] = 0; for (int s2 = 0; s2 < S_; s2++) off[s2+1] = off[s2] + cnt[s2]; }
  __syncthreads();
  if (t < S_) cur[t] = off[t];
  __syncthreads();
  for (int b = t; b < B_; b += 256){ int p = atomicAdd(&cur[ids[b]], 1); order[p] = b; }
  if (t < S_+1) starts[t] = off[t];
}

// ---------------- kernel 2: low (blocks 0..383) + GEMM (blocks 384..1151, uniform K=1024) -
// low: one m-tile per wave, k-split 2-chain ILP; low output stored bf16.
// gemm: 128^2 tile, 4 waves of 64x64, 2-phase dbuf, k-slot swizzle, bf16 Y; 6 units K=1024.
__global__ __launch_bounds__(256, 4) void gemm_low_kernel(
    const unsigned short* __restrict__ XC,
    const unsigned short* __restrict__ Wt_all,
    unsigned short* __restrict__ Yall,
    const float* __restrict__ la_ir, const float* __restrict__ la_iu,
    const float* __restrict__ la_ic, const float* __restrict__ la_rr,
    const float* __restrict__ la_ru, const float* __restrict__ la_rc,
    const int* __restrict__ starts, const int* __restrict__ order,
    unsigned short* __restrict__ lowb){
  __shared__ __align__(16) unsigned short smem[16512];   // 33 KB overlay (low LA is max)
  int t = threadIdx.x;
  int bx = blockIdx.x;

  if (bx < 384){
    // ---- low path ----
    int s = bx & 63, g = bx >> 6;
    const float* la;
    switch(g){ case 0: la=la_ir; break; case 1: la=la_iu; break; case 2: la=la_ic; break;
               case 3: la=la_rr; break; case 4: la=la_ru; break; default: la=la_rc; break; }
    int kofs = (g < 3) ? 0 : 1024;
    la += (size_t)s * D_ * R_;
    unsigned short* LA = smem;             // [r][d] 16 x 1032 (pad 8)
    for (int i4 = t; i4 < D_*R_/4; i4 += 256){
      float4 v = *(const float4*)&la[i4*4];
      int d = i4 >> 2, r0 = (i4 & 3) * 4;
      LA[(r0+0)*1032 + d] = f2b(v.x);
      LA[(r0+1)*1032 + d] = f2b(v.y);
      LA[(r0+2)*1032 + d] = f2b(v.z);
      LA[(r0+3)*1032 + d] = f2b(v.w);
    }
    __syncthreads();
    int start = starts[s], cnt = starts[s+1] - start;
    if (cnt == 0) return;
    int lane = t & 63, wave = t >> 6;
    int l15 = lane & 15, kq = (lane >> 4) * 8;
    int ntiles = (cnt + 15) >> 4;
    for (int mt = wave; mt < ntiles; mt += 4){
      int m0 = mt*16 + l15; if (m0 >= cnt) m0 = cnt - 1;
      int e0 = order[start + m0];
      const unsigned short* A0 = XC + (size_t)e0*2048 + kofs + kq;
      const unsigned short* Bp = &LA[l15*1032 + kq];
      f32x4 accA = {}, accB = {};
      #pragma unroll 4
      for (int kt = 0; kt < 512; kt += 32){
        s16x8 a0 = *(const s16x8*)(A0 + kt);
        s16x8 b0 = *(const s16x8*)(Bp + kt);
        s16x8 a1 = *(const s16x8*)(A0 + 512 + kt);
        s16x8 b1 = *(const s16x8*)(Bp + 512 + kt);
        accA = __builtin_amdgcn_mfma_f32_16x16x32_bf16(a0, b0, accA, 0, 0, 0);
        accB = __builtin_amdgcn_mfma_f32_16x16x32_bf16(a1, b1, accB, 0, 0, 0);
      }
      f32x4 acc = accA + accB;
      int rowb = (lane >> 4) * 4;
      #pragma unroll
      for (int i = 0; i < 4; i++){
        int m = mt*16 + rowb + i;
        if (m < cnt){
          int e = order[start + m];
          lowb[((size_t)g*B_ + e)*R_ + l15] = f2b(acc[i]);
        }
      }
    }
    return;
  }

  // ---- gemm path (128x128, 2-phase, uniform K=1024) ----
  int bid = bx - 384;
  int u = bid >> 7;                 // 128 blocks/unit, 6 units
  int tile = bid & 127;
  int kofs = (u & 1) << 10;         // even units read x half, odd read carry half
  const unsigned short* Wt = Wt_all + (size_t)u * 1048576;
  unsigned short* Y = Yall + (size_t)u * ((size_t)B_ * F_);

  unsigned short (*As)[4096] = (unsigned short(*)[4096])smem;           // [2][128*32]
  unsigned short (*Bs)[4096] = (unsigned short(*)[4096])(smem + 8192);  // [2][128*32]

  int lane = t & 63, wave = t >> 6;
  int mt = tile >> 3, nt = tile & 7;
  int row0 = mt * 128, col0 = nt * 128;
  int wrow = (wave >> 1) * 64, wcol = (wave & 1) * 64;

  int arow = t >> 2;
  int achk = ((t & 3) ^ ((t >> 3) & 3)) * 8;   // swizzled source k-slot

  const unsigned short* Ab  = XC + (size_t)(row0 + arow) * 2048 + kofs + achk;
  const unsigned short* Ab2 = Ab + (size_t)64 * 2048;
  const unsigned short* Bb  = Wt + (size_t)(col0 + arow) * 1024 + achk;
  const unsigned short* Bb2 = Bb + (size_t)64 * 1024;

  int l15 = lane & 15;
  int kof = (((lane >> 4) ^ ((l15 >> 1) & 3)) * 8);   // swizzled read slot
  f32x4 acc[4][4] = {};

  gload16(Ab,  &As[0][t*8]);  gload16(Ab2, &As[0][2048 + t*8]);
  gload16(Bb,  &Bs[0][t*8]);  gload16(Bb2, &Bs[0][2048 + t*8]);
  __syncthreads();

  int cur = 0;
  for (int kt = 32; kt < 1024; kt += 32){
    int nxt = cur ^ 1;
    gload16(Ab  + kt, &As[nxt][t*8]);  gload16(Ab2 + kt, &As[nxt][2048 + t*8]);
    gload16(Bb  + kt, &Bs[nxt][t*8]);  gload16(Bb2 + kt, &Bs[nxt][2048 + t*8]);
    s16x8 af[4], bfr[4];
    #pragma unroll
    for (int m = 0; m < 4; m++)
      af[m] = *(const s16x8*)&As[cur][(wrow + m*16 + l15)*32 + kof];
    #pragma unroll
    for (int n = 0; n < 4; n++)
      bfr[n] = *(const s16x8*)&Bs[cur][(wcol + n*16 + l15)*32 + kof];
    __builtin_amdgcn_s_setprio(1);
    #pragma unroll
    for (int m = 0; m < 4; m++){
      #pragma unroll
      for (int n = 0; n < 4; n++){
        acc[m][n] = __builtin_amdgcn_mfma_f32_16x16x32_bf16(af[m], bfr[n], acc[m][n], 0, 0, 0);
      }
    }
    __builtin_amdgcn_s_setprio(0);
    __syncthreads();
    cur = nxt;
  }
  {
    s16x8 af[4], bfr[4];
    #pragma unroll
    for (int m = 0; m < 4; m++)
      af[m] = *(const s16x8*)&As[cur][(wrow + m*16 + l15)*32 + kof];
    #pragma unroll
    for (int n = 0; n < 4; n++)
      bfr[n] = *(const s16x8*)&Bs[cur][(wcol + n*16 + l15)*32 + kof];
    #pragma unroll
    for (int m = 0; m < 4; m++){
      #pragma unroll
      for (int n = 0; n < 4; n++){
        acc[m][n] = __builtin_amdgcn_mfma_f32_16x16x32_bf16(af[m], bfr[n], acc[m][n], 0, 0, 0);
      }
    }
  }

  int orow = row0 + wrow + (lane >> 4) * 4;
  int ocol = col0 + wcol + l15;
  #pragma unroll
  for (int m = 0; m < 4; m++){
    #pragma unroll
    for (int n = 0; n < 4; n++){
      #pragma unroll
      for (int i = 0; i < 4; i++){
        Y[(size_t)(orow + m*16 + i) * F_ + ocol + n*16] = f2b(acc[m][n][i]);
      }
    }
  }
}

// ---------------- kernel 3: fused MFMA delta + GRU gates + output (bucketed) --------------
// dr=[low_ir|low_rr]@[lb_ir;lb_rr]; du=[low_iu|low_ru]@[lb_iu;lb_ru]
// dic=[low_ic|0]@[lb_ic;lb_rc];     drc=[0|low_rc]@[lb_ic;lb_rc]
// r=sig(Y0+Y1+b_ir+dr), u=sig(Y2+Y3+b_iu+du), cand=tanh(Y4+b_ic+dic + r*(Y5+drc))
__global__ __launch_bounds__(256) void delta_final_kernel(
    const float* __restrict__ carry,
    const float* __restrict__ bias_ir, const float* __restrict__ bias_iu,
    const float* __restrict__ bias_ic,
    const float* __restrict__ lb_ir, const float* __restrict__ lb_rr,
    const float* __restrict__ lb_iu, const float* __restrict__ lb_ru,
    const float* __restrict__ lb_ic, const float* __restrict__ lb_rc,
    const int* __restrict__ starts, const int* __restrict__ order,
    const unsigned short* __restrict__ lowb, const unsigned short* __restrict__ Yall,
    float* __restrict__ out){
  int s = blockIdx.x;
  int c0 = blockIdx.y * 128;
  __shared__ unsigned short Bsm[3 * 128 * 40];   // 3 stacked [col][k0..31], stride 40
  int t = threadIdx.x;
  const float* lbp[6] = {lb_ir, lb_rr, lb_iu, lb_ru, lb_ic, lb_rc};
  #pragma unroll
  for (int j = 0; j < 6; j++){
    const float* lb = lbp[j] + (size_t)s * R_ * F_;
    unsigned short* Bj = &Bsm[(j >> 1)*5120 + (j & 1)*16];
    #pragma unroll
    for (int it = 0; it < 2; it++){
      int idx = t + it*256;
      int r = idx >> 5, c4 = (idx & 31) * 4;
      float4 v = *(const float4*)&lb[(size_t)r*F_ + c0 + c4];
      Bj[(c4+0)*40 + r] = f2b(v.x);
      Bj[(c4+1)*40 + r] = f2b(v.y);
      Bj[(c4+2)*40 + r] = f2b(v.z);
      Bj[(c4+3)*40 + r] = f2b(v.w);
    }
  }
  __syncthreads();
  int start = starts[s], cnt = starts[s+1] - start;
  if (cnt == 0) return;
  int lane = t & 63, wave = t >> 6;
  int l15 = lane & 15, kq = (lane >> 4) * 8;   // 0,8,16,24
  int ntiles = (cnt + 15) >> 4;
  const unsigned short* Y0 = Yall + 0*(size_t)B_*F_;
  const unsigned short* Y1 = Yall + 1*(size_t)B_*F_;
  const unsigned short* Y2 = Yall + 2*(size_t)B_*F_;
  const unsigned short* Y3 = Yall + 3*(size_t)B_*F_;
  const unsigned short* Y4 = Yall + 4*(size_t)B_*F_;
  const unsigned short* Y5 = Yall + 5*(size_t)B_*F_;
  int k8 = kq & 15; bool hi = (kq >= 16);
  for (int pt = wave; pt < ntiles*2; pt += 4){
    int mt = pt >> 1, cf0 = (pt & 1) * 4;
    int m = mt*16 + l15; if (m >= cnt) m = cnt - 1;
    int e = order[start + m];
    s16x8 a_r, a_u, a_c1 = {}, a_c2 = {};
    a_r = *(const s16x8*)&lowb[((size_t)(hi ? 3 : 0)*B_ + e)*R_ + k8];
    a_u = *(const s16x8*)&lowb[((size_t)(hi ? 4 : 1)*B_ + e)*R_ + k8];
    if (!hi) a_c1 = *(const s16x8*)&lowb[((size_t)2*B_ + e)*R_ + k8];
    else     a_c2 = *(const s16x8*)&lowb[((size_t)5*B_ + e)*R_ + k8];
    int rowb = (lane >> 4) * 4;
    int erow[4]; bool wok[4];
    #pragma unroll
    for (int i = 0; i < 4; i++){
      int mm = mt*16 + rowb + i;
      wok[i] = (mm < cnt);
      erow[i] = order[start + (wok[i] ? mm : cnt - 1)];
    }
    #pragma unroll
    for (int cf = cf0; cf < cf0 + 4; cf++){
      int col = cf*16 + l15;
      s16x8 b_r = *(const s16x8*)&Bsm[0*5120 + col*40 + kq];
      s16x8 b_u = *(const s16x8*)&Bsm[1*5120 + col*40 + kq];
      s16x8 b_c = *(const s16x8*)&Bsm[2*5120 + col*40 + kq];
      f32x4 zero = {};
      f32x4 dr  = __builtin_amdgcn_mfma_f32_16x16x32_bf16(a_r,  b_r, zero, 0, 0, 0);
      f32x4 du  = __builtin_amdgcn_mfma_f32_16x16x32_bf16(a_u,  b_u, zero, 0, 0, 0);
      f32x4 dic = __builtin_amdgcn_mfma_f32_16x16x32_bf16(a_c1, b_c, zero, 0, 0, 0);
      f32x4 drc = __builtin_amdgcn_mfma_f32_16x16x32_bf16(a_c2, b_c, zero, 0, 0, 0);
      int oc = c0 + col;
      float br = bias_ir[oc], bu = bias_iu[oc], bc = bias_ic[oc];
      #pragma unroll
      for (int i = 0; i < 4; i++){
        if (wok[i]){
          size_t idx = (size_t)erow[i]*F_ + oc;
          float zr  = b2f(Y0[idx]) + b2f(Y1[idx]) + br + dr[i];
          float zu  = b2f(Y2[idx]) + b2f(Y3[idx]) + bu + du[i];
          float zic = b2f(Y4[idx]) + bc + dic[i];
          float zrc = b2f(Y5[idx]) + drc[i];
          float cv  = carry[idx];
          float rr = 1.f/(1.f+__expf(-zr));
          float uu = 1.f/(1.f+__expf(-zu));
          float a = zic + rr*zrc;
          float ee = __expf(-2.f*fabsf(a));
          float cand = copysignf((1.f-ee)/(1.f+ee), a);
          out[idx] = (1.f-uu)*cand + uu*cv;
        }
      }
    }
  }
}

extern "C" void kernel_launch(void* const* d_in, const int* in_sizes, int n_in,
                              void* d_out, int out_size, void* d_ws, size_t ws_size,
                              hipStream_t stream){
  const float* carry   = (const float*)d_in[0];
  const float* x       = (const float*)d_in[1];
  const int*   ids     = (const int*)d_in[2];
  const float* w_ir    = (const float*)d_in[3];
  const float* bias_ir = (const float*)d_in[4];
  const float* la_ir   = (const float*)d_in[5];
  const float* lb_ir   = (const float*)d_in[6];
  const float* w_iu    = (const float*)d_in[7];
  const float* bias_iu = (const float*)d_in[8];
  const float* la_iu   = (const float*)d_in[9];
  const float* lb_iu   = (const float*)d_in[10];
  const float* w_ic    = (const float*)d_in[11];
  const float* bias_ic = (const float*)d_in[12];
  const float* la_ic   = (const float*)d_in[13];
  const float* lb_ic   = (const float*)d_in[14];
  const float* w_rr    = (const float*)d_in[15];
  const float* la_rr   = (const float*)d_in[16];
  const float* lb_rr   = (const float*)d_in[17];
  const float* w_ru    = (const float*)d_in[18];
  const float* la_ru   = (const float*)d_in[19];
  const float* lb_ru   = (const float*)d_in[20];
  const float* w_rc    = (const float*)d_in[21];
  const float* la_rc   = (const float*)d_in[22];
  const float* lb_rc   = (const float*)d_in[23];

  char* ws = (char*)d_ws;
  unsigned short* XC     = (unsigned short*)(ws + 0);          // 8 MiB
  unsigned short* Wt_all = (unsigned short*)(ws + 8388608);    // 12 MiB (6 x 2 MiB)
  unsigned short* Yall   = (unsigned short*)(ws + 20971520);   // 24 MiB (6 x 4 MiB bf16)
  unsigned short* lowb   = (unsigned short*)(ws + 46137344);   // 384 KiB bf16
  int* starts = (int*)(ws + 46530560);
  int* order  = (int*)(ws + 46531584);

  prep_kernel<<<dim3(3585), dim3(256), 0, stream>>>(x, carry, XC,
                                                    w_ir, w_rr, w_iu, w_ru, w_ic, w_rc,
                                                    Wt_all, ids, starts, order);
  gemm_low_kernel<<<dim3(1152), dim3(256), 0, stream>>>(XC, Wt_all, Yall,
                                                        la_ir, la_iu, la_ic,
                                                        la_rr, la_ru, la_rc,
                                                        starts, order, lowb);
  delta_final_kernel<<<dim3(64, 8), dim3(256), 0, stream>>>(carry, bias_ir, bias_iu, bias_ic,
                                                            lb_ir, lb_rr, lb_iu, lb_ru,
                                                            lb_ic, lb_rc,
                                                            starts, order, lowb, Yall,
                                                            (float*)d_out);
}

// Round 11
// 81.241 us; speedup vs baseline: 1.1060x; 1.1060x over previous
//
#include <hip/hip_runtime.h>
#include <stdint.h>

#define B_  2048
#define D_  1024
#define F_  1024
#define S_  64
#define R_  16

typedef __attribute__((ext_vector_type(8))) short  s16x8;
typedef __attribute__((ext_vector_type(4))) unsigned short u16x4;
typedef __attribute__((ext_vector_type(8))) unsigned short u16x8;
typedef __attribute__((ext_vector_type(4))) float  f32x4;

__device__ __forceinline__ unsigned short f2b(float f){
  unsigned u = __float_as_uint(f);
  u = u + 0x7fffu + ((u >> 16) & 1u);   // RNE to bf16
  return (unsigned short)(u >> 16);
}
__device__ __forceinline__ float b2f(unsigned short s){
  return __uint_as_float(((unsigned)s) << 16);
}

__device__ __forceinline__ void gload16(const void* g, void* l){
  __builtin_amdgcn_global_load_lds((const __attribute__((address_space(1))) unsigned int*)g,
                                   (__attribute__((address_space(3))) unsigned int*)l, 16, 0, 0);
}

// Wt_all element offsets: W0t(ir+rr,K2048)=0, W1t(iu+ru,K2048)=2M, W2t(ic,K1024)=4M, W3t(rc)=5M
#define W0OFF 0
#define W1OFF 2097152
#define W2OFF 4194304
#define W3OFF 5242880

// low g order: 0=ir 1=iu 2=ic 3=rr 4=ru 5=rc

// ---------------- kernel 1: fused prep = cast_xc | wcast | bucket (block-partitioned) -----
__global__ __launch_bounds__(256) void prep_kernel(
    const float* __restrict__ x, const float* __restrict__ carry,
    unsigned short* __restrict__ XC,
    const float* __restrict__ w_ir, const float* __restrict__ w_rr,
    const float* __restrict__ w_iu, const float* __restrict__ w_ru,
    const float* __restrict__ w_ic, const float* __restrict__ w_rc,
    unsigned short* __restrict__ Wt_all,
    const int* __restrict__ ids, int* __restrict__ starts, int* __restrict__ order){
  int bx = blockIdx.x;
  int t = threadIdx.x;
  if (bx < 2048){
    int i = bx * 256 + t;
    int b = i >> 8;
    int j = (i & 255) * 4;
    float4 xv = *(const float4*)&x[(size_t)b*D_ + j];
    float4 cv = *(const float4*)&carry[(size_t)b*F_ + j];
    u16x4 xs, cs;
    xs[0]=f2b(xv.x); xs[1]=f2b(xv.y); xs[2]=f2b(xv.z); xs[3]=f2b(xv.w);
    cs[0]=f2b(cv.x); cs[1]=f2b(cv.y); cs[2]=f2b(cv.z); cs[3]=f2b(cv.w);
    *(u16x4*)&XC[(size_t)b*2048 + j]        = xs;
    *(u16x4*)&XC[(size_t)b*2048 + 1024 + j] = cs;
    return;
  }
  if (bx < 3584){
    int wb = bx - 2048;
    int g = wb >> 8, xb = wb & 255;
    const float* W; unsigned short* O; int st, ko;
    switch(g){
      case 0:  W=w_ir; O=Wt_all+W0OFF; st=2048; ko=0;    break;
      case 1:  W=w_rr; O=Wt_all+W0OFF; st=2048; ko=1024; break;
      case 2:  W=w_iu; O=Wt_all+W1OFF; st=2048; ko=0;    break;
      case 3:  W=w_ru; O=Wt_all+W1OFF; st=2048; ko=1024; break;
      case 4:  W=w_ic; O=Wt_all+W2OFF; st=1024; ko=0;    break;
      default: W=w_rc; O=Wt_all+W3OFF; st=1024; ko=0;    break;
    }
    __shared__ unsigned short T[64][72];   // row stride 144B (9*16B)
    int n0 = (xb & 15) * 64;
    int k0 = (xb >> 4) * 64;
    int c4 = (t & 15) * 4;
    int kk = t >> 4;
    #pragma unroll
    for (int i = 0; i < 4; i++){
      int k = kk + i*16;
      float4 v = *(const float4*)&W[(size_t)(k0+k)*F_ + n0 + c4];
      T[c4+0][k] = f2b(v.x); T[c4+1][k] = f2b(v.y); T[c4+2][k] = f2b(v.z); T[c4+3][k] = f2b(v.w);
    }
    __syncthreads();
    int n = t >> 2, ch = (t & 3) * 16;
    u16x8 a = *(const u16x8*)&T[n][ch];
    u16x8 b = *(const u16x8*)&T[n][ch+8];
    *(u16x8*)&O[(size_t)(n0+n)*st + ko + k0 + ch]     = a;
    *(u16x8*)&O[(size_t)(n0+n)*st + ko + k0 + ch + 8] = b;
    return;
  }
  // bucket
  __shared__ int cnt[S_]; __shared__ int off[S_+1]; __shared__ int cur[S_];
  if (t < S_) cnt[t] = 0;
  __syncthreads();
  for (int b = t; b < B_; b += 256) atomicAdd(&cnt[ids[b]], 1);
  __syncthreads();
  if (t == 0){ off[0] = 0; for (int s2 = 0; s2 < S_; s2++) off[s2+1] = off[s2] + cnt[s2]; }
  __syncthreads();
  if (t < S_) cur[t] = off[t];
  __syncthreads();
  for (int b = t; b < B_; b += 256){ int p = atomicAdd(&cur[ids[b]], 1); order[p] = b; }
  if (t < S_+1) starts[t] = off[t];
}

// ---------------- kernel 2: GEMM (blocks 0..511, 128x128 tiles) + low (512..895) ----------
// gemm: r9-winning shape — 128^2 tile, 4 waves of 64x64, 2-phase dbuf, k-slot swizzle,
//       bf16 Y; units u0/u1 K=2048 (merged ir+rr / iu+ru) first, u2/u3 K=1024.
// low: one m-tile per wave, k-split 2-chain ILP, bf16 output.
// Total smem 33 KB (low LA is max) -> 4 blocks/CU.
__global__ __launch_bounds__(256, 4) void gemm_low_kernel(
    const unsigned short* __restrict__ XC,
    const unsigned short* __restrict__ Wt_all,
    unsigned short* __restrict__ Yall,
    const float* __restrict__ la_ir, const float* __restrict__ la_iu,
    const float* __restrict__ la_ic, const float* __restrict__ la_rr,
    const float* __restrict__ la_ru, const float* __restrict__ la_rc,
    const int* __restrict__ starts, const int* __restrict__ order,
    unsigned short* __restrict__ lowb){
  __shared__ __align__(16) unsigned short smem[16512];   // 33 KB overlay (low LA is max)
  int t = threadIdx.x;
  int bx = blockIdx.x;

  if (bx >= 512){
    // ---- low path ----
    int lb = bx - 512;
    int s = lb & 63, g = lb >> 6;
    const float* la;
    switch(g){ case 0: la=la_ir; break; case 1: la=la_iu; break; case 2: la=la_ic; break;
               case 3: la=la_rr; break; case 4: la=la_ru; break; default: la=la_rc; break; }
    int kofs = (g < 3) ? 0 : 1024;
    la += (size_t)s * D_ * R_;
    unsigned short* LA = smem;             // [r][d] 16 x 1032 (pad 8)
    for (int i4 = t; i4 < D_*R_/4; i4 += 256){
      float4 v = *(const float4*)&la[i4*4];
      int d = i4 >> 2, r0 = (i4 & 3) * 4;
      LA[(r0+0)*1032 + d] = f2b(v.x);
      LA[(r0+1)*1032 + d] = f2b(v.y);
      LA[(r0+2)*1032 + d] = f2b(v.z);
      LA[(r0+3)*1032 + d] = f2b(v.w);
    }
    __syncthreads();
    int start = starts[s], cnt = starts[s+1] - start;
    if (cnt == 0) return;
    int lane = t & 63, wave = t >> 6;
    int l15 = lane & 15, kq = (lane >> 4) * 8;
    int ntiles = (cnt + 15) >> 4;
    for (int mt = wave; mt < ntiles; mt += 4){
      int m0 = mt*16 + l15; if (m0 >= cnt) m0 = cnt - 1;
      int e0 = order[start + m0];
      const unsigned short* A0 = XC + (size_t)e0*2048 + kofs + kq;
      const unsigned short* Bp = &LA[l15*1032 + kq];
      f32x4 accA = {}, accB = {};
      #pragma unroll 4
      for (int kt = 0; kt < 512; kt += 32){
        s16x8 a0 = *(const s16x8*)(A0 + kt);
        s16x8 b0 = *(const s16x8*)(Bp + kt);
        s16x8 a1 = *(const s16x8*)(A0 + 512 + kt);
        s16x8 b1 = *(const s16x8*)(Bp + 512 + kt);
        accA = __builtin_amdgcn_mfma_f32_16x16x32_bf16(a0, b0, accA, 0, 0, 0);
        accB = __builtin_amdgcn_mfma_f32_16x16x32_bf16(a1, b1, accB, 0, 0, 0);
      }
      f32x4 acc = accA + accB;
      int rowb = (lane >> 4) * 4;
      #pragma unroll
      for (int i = 0; i < 4; i++){
        int m = mt*16 + rowb + i;
        if (m < cnt){
          int e = order[start + m];
          lowb[((size_t)g*B_ + e)*R_ + l15] = f2b(acc[i]);
        }
      }
    }
    return;
  }

  // ---- gemm path (128x128, 2-phase) ----
  int u = bx >> 7;                  // 128 blocks/unit; K=2048 units first
  int tile = bx & 127;
  int K = (u < 2) ? 2048 : 1024;
  int kofs = (u == 3) ? 1024 : 0;
  const size_t uoffs[4] = {W0OFF, W1OFF, W2OFF, W3OFF};
  const unsigned short* Wt = Wt_all + uoffs[u];
  unsigned short* Y = Yall + (size_t)u * ((size_t)B_ * F_);

  unsigned short (*As)[4096] = (unsigned short(*)[4096])smem;           // [2][128*32]
  unsigned short (*Bs)[4096] = (unsigned short(*)[4096])(smem + 8192);  // [2][128*32]

  int lane = t & 63, wave = t >> 6;
  int mt = tile >> 3, nt = tile & 7;
  int row0 = mt * 128, col0 = nt * 128;
  int wrow = (wave >> 1) * 64, wcol = (wave & 1) * 64;

  int arow = t >> 2;
  int achk = ((t & 3) ^ ((t >> 3) & 3)) * 8;   // swizzled source k-slot

  const unsigned short* Ab  = XC + (size_t)(row0 + arow) * 2048 + kofs + achk;
  const unsigned short* Ab2 = Ab + (size_t)64 * 2048;
  const unsigned short* Bb  = Wt + (size_t)(col0 + arow) * K + achk;
  const unsigned short* Bb2 = Bb + (size_t)64 * K;

  int l15 = lane & 15;
  int kof = (((lane >> 4) ^ ((l15 >> 1) & 3)) * 8);   // swizzled read slot
  f32x4 acc[4][4] = {};

  gload16(Ab,  &As[0][t*8]);  gload16(Ab2, &As[0][2048 + t*8]);
  gload16(Bb,  &Bs[0][t*8]);  gload16(Bb2, &Bs[0][2048 + t*8]);
  __syncthreads();

  int cur = 0;
  for (int kt = 32; kt < K; kt += 32){
    int nxt = cur ^ 1;
    gload16(Ab  + kt, &As[nxt][t*8]);  gload16(Ab2 + kt, &As[nxt][2048 + t*8]);
    gload16(Bb  + kt, &Bs[nxt][t*8]);  gload16(Bb2 + kt, &Bs[nxt][2048 + t*8]);
    s16x8 af[4], bfr[4];
    #pragma unroll
    for (int m = 0; m < 4; m++)
      af[m] = *(const s16x8*)&As[cur][(wrow + m*16 + l15)*32 + kof];
    #pragma unroll
    for (int n = 0; n < 4; n++)
      bfr[n] = *(const s16x8*)&Bs[cur][(wcol + n*16 + l15)*32 + kof];
    __builtin_amdgcn_s_setprio(1);
    #pragma unroll
    for (int m = 0; m < 4; m++){
      #pragma unroll
      for (int n = 0; n < 4; n++){
        acc[m][n] = __builtin_amdgcn_mfma_f32_16x16x32_bf16(af[m], bfr[n], acc[m][n], 0, 0, 0);
      }
    }
    __builtin_amdgcn_s_setprio(0);
    __syncthreads();
    cur = nxt;
  }
  {
    s16x8 af[4], bfr[4];
    #pragma unroll
    for (int m = 0; m < 4; m++)
      af[m] = *(const s16x8*)&As[cur][(wrow + m*16 + l15)*32 + kof];
    #pragma unroll
    for (int n = 0; n < 4; n++)
      bfr[n] = *(const s16x8*)&Bs[cur][(wcol + n*16 + l15)*32 + kof];
    #pragma unroll
    for (int m = 0; m < 4; m++){
      #pragma unroll
      for (int n = 0; n < 4; n++){
        acc[m][n] = __builtin_amdgcn_mfma_f32_16x16x32_bf16(af[m], bfr[n], acc[m][n], 0, 0, 0);
      }
    }
  }

  int orow = row0 + wrow + (lane >> 4) * 4;
  int ocol = col0 + wcol + l15;
  #pragma unroll
  for (int m = 0; m < 4; m++){
    #pragma unroll
    for (int n = 0; n < 4; n++){
      #pragma unroll
      for (int i = 0; i < 4; i++){
        Y[(size_t)(orow + m*16 + i) * F_ + ocol + n*16] = f2b(acc[m][n][i]);
      }
    }
  }
}

// ---------------- kernel 3: fused MFMA delta + GRU gates + output (bucketed, bf16) --------
// dr=[low_ir|low_rr]@[lb_ir;lb_rr]; du=[low_iu|low_ru]@[lb_iu;lb_ru]
// dic=[low_ic|0]@[lb_ic;lb_rc];     drc=[0|low_rc]@[lb_ic;lb_rc]
// r=sig(Y0+b_ir+dr), u=sig(Y1+b_iu+du), cand=tanh(Y2+b_ic+dic + r*(Y3+drc))
__global__ __launch_bounds__(256) void delta_final_kernel(
    const float* __restrict__ carry,
    const float* __restrict__ bias_ir, const float* __restrict__ bias_iu,
    const float* __restrict__ bias_ic,
    const float* __restrict__ lb_ir, const float* __restrict__ lb_rr,
    const float* __restrict__ lb_iu, const float* __restrict__ lb_ru,
    const float* __restrict__ lb_ic, const float* __restrict__ lb_rc,
    const int* __restrict__ starts, const int* __restrict__ order,
    const unsigned short* __restrict__ lowb, const unsigned short* __restrict__ Yall,
    float* __restrict__ out){
  int s = blockIdx.x;
  int c0 = blockIdx.y * 128;
  __shared__ unsigned short Bsm[3 * 128 * 40];   // 3 stacked [col][k0..31], stride 40
  int t = threadIdx.x;
  const float* lbp[6] = {lb_ir, lb_rr, lb_iu, lb_ru, lb_ic, lb_rc};
  #pragma unroll
  for (int j = 0; j < 6; j++){
    const float* lb = lbp[j] + (size_t)s * R_ * F_;
    unsigned short* Bj = &Bsm[(j >> 1)*5120 + (j & 1)*16];
    #pragma unroll
    for (int it = 0; it < 2; it++){
      int idx = t + it*256;
      int r = idx >> 5, c4 = (idx & 31) * 4;
      float4 v = *(const float4*)&lb[(size_t)r*F_ + c0 + c4];
      Bj[(c4+0)*40 + r] = f2b(v.x);
      Bj[(c4+1)*40 + r] = f2b(v.y);
      Bj[(c4+2)*40 + r] = f2b(v.z);
      Bj[(c4+3)*40 + r] = f2b(v.w);
    }
  }
  __syncthreads();
  int start = starts[s], cnt = starts[s+1] - start;
  if (cnt == 0) return;
  int lane = t & 63, wave = t >> 6;
  int l15 = lane & 15, kq = (lane >> 4) * 8;   // 0,8,16,24
  int ntiles = (cnt + 15) >> 4;
  const unsigned short* Y0 = Yall + 0*(size_t)B_*F_;
  const unsigned short* Y1 = Yall + 1*(size_t)B_*F_;
  const unsigned short* Y2 = Yall + 2*(size_t)B_*F_;
  const unsigned short* Y3 = Yall + 3*(size_t)B_*F_;
  int k8 = kq & 15; bool hi = (kq >= 16);
  for (int pt = wave; pt < ntiles*2; pt += 4){
    int mt = pt >> 1, cf0 = (pt & 1) * 4;
    int m = mt*16 + l15; if (m >= cnt) m = cnt - 1;
    int e = order[start + m];
    s16x8 a_r, a_u, a_c1 = {}, a_c2 = {};
    a_r = *(const s16x8*)&lowb[((size_t)(hi ? 3 : 0)*B_ + e)*R_ + k8];
    a_u = *(const s16x8*)&lowb[((size_t)(hi ? 4 : 1)*B_ + e)*R_ + k8];
    if (!hi) a_c1 = *(const s16x8*)&lowb[((size_t)2*B_ + e)*R_ + k8];
    else     a_c2 = *(const s16x8*)&lowb[((size_t)5*B_ + e)*R_ + k8];
    int rowb = (lane >> 4) * 4;
    int erow[4]; bool wok[4];
    #pragma unroll
    for (int i = 0; i < 4; i++){
      int mm = mt*16 + rowb + i;
      wok[i] = (mm < cnt);
      erow[i] = order[start + (wok[i] ? mm : cnt - 1)];
    }
    #pragma unroll
    for (int cf = cf0; cf < cf0 + 4; cf++){
      int col = cf*16 + l15;
      s16x8 b_r = *(const s16x8*)&Bsm[0*5120 + col*40 + kq];
      s16x8 b_u = *(const s16x8*)&Bsm[1*5120 + col*40 + kq];
      s16x8 b_c = *(const s16x8*)&Bsm[2*5120 + col*40 + kq];
      f32x4 zero = {};
      f32x4 dr  = __builtin_amdgcn_mfma_f32_16x16x32_bf16(a_r,  b_r, zero, 0, 0, 0);
      f32x4 du  = __builtin_amdgcn_mfma_f32_16x16x32_bf16(a_u,  b_u, zero, 0, 0, 0);
      f32x4 dic = __builtin_amdgcn_mfma_f32_16x16x32_bf16(a_c1, b_c, zero, 0, 0, 0);
      f32x4 drc = __builtin_amdgcn_mfma_f32_16x16x32_bf16(a_c2, b_c, zero, 0, 0, 0);
      int oc = c0 + col;
      float br = bias_ir[oc], bu = bias_iu[oc], bc = bias_ic[oc];
      #pragma unroll
      for (int i = 0; i < 4; i++){
        if (wok[i]){
          size_t idx = (size_t)erow[i]*F_ + oc;
          float zr  = b2f(Y0[idx]) + br + dr[i];
          float zu  = b2f(Y1[idx]) + bu + du[i];
          float zic = b2f(Y2[idx]) + bc + dic[i];
          float zrc = b2f(Y3[idx]) + drc[i];
          float cv  = carry[idx];
          float rr = 1.f/(1.f+__expf(-zr));
          float uu = 1.f/(1.f+__expf(-zu));
          float a = zic + rr*zrc;
          float ee = __expf(-2.f*fabsf(a));
          float cand = copysignf((1.f-ee)/(1.f+ee), a);
          out[idx] = (1.f-uu)*cand + uu*cv;
        }
      }
    }
  }
}

extern "C" void kernel_launch(void* const* d_in, const int* in_sizes, int n_in,
                              void* d_out, int out_size, void* d_ws, size_t ws_size,
                              hipStream_t stream){
  const float* carry   = (const float*)d_in[0];
  const float* x       = (const float*)d_in[1];
  const int*   ids     = (const int*)d_in[2];
  const float* w_ir    = (const float*)d_in[3];
  const float* bias_ir = (const float*)d_in[4];
  const float* la_ir   = (const float*)d_in[5];
  const float* lb_ir   = (const float*)d_in[6];
  const float* w_iu    = (const float*)d_in[7];
  const float* bias_iu = (const float*)d_in[8];
  const float* la_iu   = (const float*)d_in[9];
  const float* lb_iu   = (const float*)d_in[10];
  const float* w_ic    = (const float*)d_in[11];
  const float* bias_ic = (const float*)d_in[12];
  const float* la_ic   = (const float*)d_in[13];
  const float* lb_ic   = (const float*)d_in[14];
  const float* w_rr    = (const float*)d_in[15];
  const float* la_rr   = (const float*)d_in[16];
  const float* lb_rr   = (const float*)d_in[17];
  const float* w_ru    = (const float*)d_in[18];
  const float* la_ru   = (const float*)d_in[19];
  const float* lb_ru   = (const float*)d_in[20];
  const float* w_rc    = (const float*)d_in[21];
  const float* la_rc   = (const float*)d_in[22];
  const float* lb_rc   = (const float*)d_in[23];

  char* ws = (char*)d_ws;
  unsigned short* XC     = (unsigned short*)(ws + 0);          // 8 MiB
  unsigned short* Wt_all = (unsigned short*)(ws + 8388608);    // 12 MiB
  unsigned short* Yall   = (unsigned short*)(ws + 20971520);   // 16 MiB (4 x 4 MiB bf16)
  unsigned short* lowb   = (unsigned short*)(ws + 37748736);   // 384 KiB bf16
  int* starts = (int*)(ws + 38141952);
  int* order  = (int*)(ws + 38142976);

  prep_kernel<<<dim3(3585), dim3(256), 0, stream>>>(x, carry, XC,
                                                    w_ir, w_rr, w_iu, w_ru, w_ic, w_rc,
                                                    Wt_all, ids, starts, order);
  gemm_low_kernel<<<dim3(896), dim3(256), 0, stream>>>(XC, Wt_all, Yall,
                                                       la_ir, la_iu, la_ic,
                                                       la_rr, la_ru, la_rc,
                                                       starts, order, lowb);
  delta_final_kernel<<<dim3(64, 8), dim3(256), 0, stream>>>(carry, bias_ir, bias_iu, bias_ic,
                                                            lb_ir, lb_rr, lb_iu, lb_ru,
                                                            lb_ic, lb_rc,
                                                            starts, order, lowb, Yall,
                                                            (float*)d_out);
}

// Round 12
// 78.217 us; speedup vs baseline: 1.1487x; 1.0387x over previous
//
#include <hip/hip_runtime.h>
#include <stdint.h>

#define B_  2048
#define D_  1024
#define F_  1024
#define S_  64
#define R_  16

typedef __attribute__((ext_vector_type(8))) short  s16x8;
typedef __attribute__((ext_vector_type(4))) unsigned short u16x4;
typedef __attribute__((ext_vector_type(8))) unsigned short u16x8;
typedef __attribute__((ext_vector_type(4))) float  f32x4;

__device__ __forceinline__ unsigned short f2b(float f){
  unsigned u = __float_as_uint(f);
  u = u + 0x7fffu + ((u >> 16) & 1u);   // RNE to bf16
  return (unsigned short)(u >> 16);
}
__device__ __forceinline__ float b2f(unsigned short s){
  return __uint_as_float(((unsigned)s) << 16);
}

__device__ __forceinline__ void gload16(const void* g, void* l){
  __builtin_amdgcn_global_load_lds((const __attribute__((address_space(1))) unsigned int*)g,
                                   (__attribute__((address_space(3))) unsigned int*)l, 16, 0, 0);
}

// Wt_all element offsets: W0t(ir+rr,K2048)=0, W1t(iu+ru,K2048)=2M, W2t(ic,K1024)=4M, W3t(rc)=5M
#define W0OFF 0
#define W1OFF 2097152
#define W2OFF 4194304
#define W3OFF 5242880

// low g order: 0=ir 1=iu 2=ic 3=rr 4=ru 5=rc

// ---------------- kernel 1: fused prep = cast_xc | wcast | bucket (block-partitioned) -----
__global__ __launch_bounds__(256) void prep_kernel(
    const float* __restrict__ x, const float* __restrict__ carry,
    unsigned short* __restrict__ XC,
    const float* __restrict__ w_ir, const float* __restrict__ w_rr,
    const float* __restrict__ w_iu, const float* __restrict__ w_ru,
    const float* __restrict__ w_ic, const float* __restrict__ w_rc,
    unsigned short* __restrict__ Wt_all,
    const int* __restrict__ ids, int* __restrict__ starts, int* __restrict__ order){
  int bx = blockIdx.x;
  int t = threadIdx.x;
  if (bx < 2048){
    int i = bx * 256 + t;
    int b = i >> 8;
    int j = (i & 255) * 4;
    float4 xv = *(const float4*)&x[(size_t)b*D_ + j];
    float4 cv = *(const float4*)&carry[(size_t)b*F_ + j];
    u16x4 xs, cs;
    xs[0]=f2b(xv.x); xs[1]=f2b(xv.y); xs[2]=f2b(xv.z); xs[3]=f2b(xv.w);
    cs[0]=f2b(cv.x); cs[1]=f2b(cv.y); cs[2]=f2b(cv.z); cs[3]=f2b(cv.w);
    *(u16x4*)&XC[(size_t)b*2048 + j]        = xs;
    *(u16x4*)&XC[(size_t)b*2048 + 1024 + j] = cs;
    return;
  }
  if (bx < 3584){
    int wb = bx - 2048;
    int g = wb >> 8, xb = wb & 255;
    const float* W; unsigned short* O; int st, ko;
    switch(g){
      case 0:  W=w_ir; O=Wt_all+W0OFF; st=2048; ko=0;    break;
      case 1:  W=w_rr; O=Wt_all+W0OFF; st=2048; ko=1024; break;
      case 2:  W=w_iu; O=Wt_all+W1OFF; st=2048; ko=0;    break;
      case 3:  W=w_ru; O=Wt_all+W1OFF; st=2048; ko=1024; break;
      case 4:  W=w_ic; O=Wt_all+W2OFF; st=1024; ko=0;    break;
      default: W=w_rc; O=Wt_all+W3OFF; st=1024; ko=0;    break;
    }
    __shared__ unsigned short T[64][72];   // row stride 144B (9*16B)
    int n0 = (xb & 15) * 64;
    int k0 = (xb >> 4) * 64;
    int c4 = (t & 15) * 4;
    int kk = t >> 4;
    #pragma unroll
    for (int i = 0; i < 4; i++){
      int k = kk + i*16;
      float4 v = *(const float4*)&W[(size_t)(k0+k)*F_ + n0 + c4];
      T[c4+0][k] = f2b(v.x); T[c4+1][k] = f2b(v.y); T[c4+2][k] = f2b(v.z); T[c4+3][k] = f2b(v.w);
    }
    __syncthreads();
    int n = t >> 2, ch = (t & 3) * 16;
    u16x8 a = *(const u16x8*)&T[n][ch];
    u16x8 b = *(const u16x8*)&T[n][ch+8];
    *(u16x8*)&O[(size_t)(n0+n)*st + ko + k0 + ch]     = a;
    *(u16x8*)&O[(size_t)(n0+n)*st + ko + k0 + ch + 8] = b;
    return;
  }
  // bucket
  __shared__ int cnt[S_]; __shared__ int off[S_+1]; __shared__ int cur[S_];
  if (t < S_) cnt[t] = 0;
  __syncthreads();
  for (int b = t; b < B_; b += 256) atomicAdd(&cnt[ids[b]], 1);
  __syncthreads();
  if (t == 0){ off[0] = 0; for (int s2 = 0; s2 < S_; s2++) off[s2+1] = off[s2] + cnt[s2]; }
  __syncthreads();
  if (t < S_) cur[t] = off[t];
  __syncthreads();
  for (int b = t; b < B_; b += 256){ int p = atomicAdd(&cur[ids[b]], 1); order[p] = b; }
  if (t < S_+1) starts[t] = off[t];
}

// ---------------- kernel 2: GEMM (blocks 0..511, XCD-swizzled) + low (512..895) -----------
// gemm: 128^2 tile, 4 waves of 64x64, 2-phase dbuf, k-slot swizzle, bf16 Y;
//       units u0/u1 K=2048 (merged ir+rr / iu+ru) first, u2/u3 K=1024.
//       Block-id swizzle (512 = 8 XCD x 64): XCD k gets 64 consecutive tiles -> A/B panel
//       reuse lands in one XCD's L2 instead of being spread across 8.
// low: one m-tile per wave, k-split 2-chain ILP, bf16 output.
__global__ __launch_bounds__(256, 4) void gemm_low_kernel(
    const unsigned short* __restrict__ XC,
    const unsigned short* __restrict__ Wt_all,
    unsigned short* __restrict__ Yall,
    const float* __restrict__ la_ir, const float* __restrict__ la_iu,
    const float* __restrict__ la_ic, const float* __restrict__ la_rr,
    const float* __restrict__ la_ru, const float* __restrict__ la_rc,
    const int* __restrict__ starts, const int* __restrict__ order,
    unsigned short* __restrict__ lowb){
  __shared__ __align__(16) unsigned short smem[16512];   // 33 KB overlay (low LA is max)
  int t = threadIdx.x;
  int bx = blockIdx.x;

  if (bx >= 512){
    // ---- low path ----
    int lb = bx - 512;
    int s = lb & 63, g = lb >> 6;
    const float* la;
    switch(g){ case 0: la=la_ir; break; case 1: la=la_iu; break; case 2: la=la_ic; break;
               case 3: la=la_rr; break; case 4: la=la_ru; break; default: la=la_rc; break; }
    int kofs = (g < 3) ? 0 : 1024;
    la += (size_t)s * D_ * R_;
    unsigned short* LA = smem;             // [r][d] 16 x 1032 (pad 8)
    for (int i4 = t; i4 < D_*R_/4; i4 += 256){
      float4 v = *(const float4*)&la[i4*4];
      int d = i4 >> 2, r0 = (i4 & 3) * 4;
      LA[(r0+0)*1032 + d] = f2b(v.x);
      LA[(r0+1)*1032 + d] = f2b(v.y);
      LA[(r0+2)*1032 + d] = f2b(v.z);
      LA[(r0+3)*1032 + d] = f2b(v.w);
    }
    __syncthreads();
    int start = starts[s], cnt = starts[s+1] - start;
    if (cnt == 0) return;
    int lane = t & 63, wave = t >> 6;
    int l15 = lane & 15, kq = (lane >> 4) * 8;
    int ntiles = (cnt + 15) >> 4;
    for (int mt = wave; mt < ntiles; mt += 4){
      int m0 = mt*16 + l15; if (m0 >= cnt) m0 = cnt - 1;
      int e0 = order[start + m0];
      const unsigned short* A0 = XC + (size_t)e0*2048 + kofs + kq;
      const unsigned short* Bp = &LA[l15*1032 + kq];
      f32x4 accA = {}, accB = {};
      #pragma unroll 4
      for (int kt = 0; kt < 512; kt += 32){
        s16x8 a0 = *(const s16x8*)(A0 + kt);
        s16x8 b0 = *(const s16x8*)(Bp + kt);
        s16x8 a1 = *(const s16x8*)(A0 + 512 + kt);
        s16x8 b1 = *(const s16x8*)(Bp + 512 + kt);
        accA = __builtin_amdgcn_mfma_f32_16x16x32_bf16(a0, b0, accA, 0, 0, 0);
        accB = __builtin_amdgcn_mfma_f32_16x16x32_bf16(a1, b1, accB, 0, 0, 0);
      }
      f32x4 acc = accA + accB;
      int rowb = (lane >> 4) * 4;
      #pragma unroll
      for (int i = 0; i < 4; i++){
        int m = mt*16 + rowb + i;
        if (m < cnt){
          int e = order[start + m];
          lowb[((size_t)g*B_ + e)*R_ + l15] = f2b(acc[i]);
        }
      }
    }
    return;
  }

  // ---- gemm path (128x128, 2-phase), XCD-chunked block id ----
  int bid = (bx & 7) * 64 + (bx >> 3);   // bijective over [0,512): XCD k <- chunk k
  int u = bid >> 7;                      // 128 blocks/unit; K=2048 units first
  int tile = bid & 127;
  int K = (u < 2) ? 2048 : 1024;
  int kofs = (u == 3) ? 1024 : 0;
  const size_t uoffs[4] = {W0OFF, W1OFF, W2OFF, W3OFF};
  const unsigned short* Wt = Wt_all + uoffs[u];
  unsigned short* Y = Yall + (size_t)u * ((size_t)B_ * F_);

  unsigned short (*As)[4096] = (unsigned short(*)[4096])smem;           // [2][128*32]
  unsigned short (*Bs)[4096] = (unsigned short(*)[4096])(smem + 8192);  // [2][128*32]

  int lane = t & 63, wave = t >> 6;
  int mt = tile >> 3, nt = tile & 7;
  int row0 = mt * 128, col0 = nt * 128;
  int wrow = (wave >> 1) * 64, wcol = (wave & 1) * 64;

  int arow = t >> 2;
  int achk = ((t & 3) ^ ((t >> 3) & 3)) * 8;   // swizzled source k-slot

  const unsigned short* Ab  = XC + (size_t)(row0 + arow) * 2048 + kofs + achk;
  const unsigned short* Ab2 = Ab + (size_t)64 * 2048;
  const unsigned short* Bb  = Wt + (size_t)(col0 + arow) * K + achk;
  const unsigned short* Bb2 = Bb + (size_t)64 * K;

  int l15 = lane & 15;
  int kof = (((lane >> 4) ^ ((l15 >> 1) & 3)) * 8);   // swizzled read slot
  f32x4 acc[4][4] = {};

  gload16(Ab,  &As[0][t*8]);  gload16(Ab2, &As[0][2048 + t*8]);
  gload16(Bb,  &Bs[0][t*8]);  gload16(Bb2, &Bs[0][2048 + t*8]);
  __syncthreads();

  int cur = 0;
  for (int kt = 32; kt < K; kt += 32){
    int nxt = cur ^ 1;
    gload16(Ab  + kt, &As[nxt][t*8]);  gload16(Ab2 + kt, &As[nxt][2048 + t*8]);
    gload16(Bb  + kt, &Bs[nxt][t*8]);  gload16(Bb2 + kt, &Bs[nxt][2048 + t*8]);
    s16x8 af[4], bfr[4];
    #pragma unroll
    for (int m = 0; m < 4; m++)
      af[m] = *(const s16x8*)&As[cur][(wrow + m*16 + l15)*32 + kof];
    #pragma unroll
    for (int n = 0; n < 4; n++)
      bfr[n] = *(const s16x8*)&Bs[cur][(wcol + n*16 + l15)*32 + kof];
    __builtin_amdgcn_s_setprio(1);
    #pragma unroll
    for (int m = 0; m < 4; m++){
      #pragma unroll
      for (int n = 0; n < 4; n++){
        acc[m][n] = __builtin_amdgcn_mfma_f32_16x16x32_bf16(af[m], bfr[n], acc[m][n], 0, 0, 0);
      }
    }
    __builtin_amdgcn_s_setprio(0);
    __syncthreads();
    cur = nxt;
  }
  {
    s16x8 af[4], bfr[4];
    #pragma unroll
    for (int m = 0; m < 4; m++)
      af[m] = *(const s16x8*)&As[cur][(wrow + m*16 + l15)*32 + kof];
    #pragma unroll
    for (int n = 0; n < 4; n++)
      bfr[n] = *(const s16x8*)&Bs[cur][(wcol + n*16 + l15)*32 + kof];
    #pragma unroll
    for (int m = 0; m < 4; m++){
      #pragma unroll
      for (int n = 0; n < 4; n++){
        acc[m][n] = __builtin_amdgcn_mfma_f32_16x16x32_bf16(af[m], bfr[n], acc[m][n], 0, 0, 0);
      }
    }
  }

  int orow = row0 + wrow + (lane >> 4) * 4;
  int ocol = col0 + wcol + l15;
  #pragma unroll
  for (int m = 0; m < 4; m++){
    #pragma unroll
    for (int n = 0; n < 4; n++){
      #pragma unroll
      for (int i = 0; i < 4; i++){
        Y[(size_t)(orow + m*16 + i) * F_ + ocol + n*16] = f2b(acc[m][n][i]);
      }
    }
  }
}

// ---------------- kernel 3: fused MFMA delta + GRU gates + output (bucketed, bf16) --------
// 64-col tiles, grid (64 ids, 16): 2x parallelism vs r11, half the per-block staging.
// dr=[low_ir|low_rr]@[lb_ir;lb_rr]; du=[low_iu|low_ru]@[lb_iu;lb_ru]
// dic=[low_ic|0]@[lb_ic;lb_rc];     drc=[0|low_rc]@[lb_ic;lb_rc]
// r=sig(Y0+b_ir+dr), u=sig(Y1+b_iu+du), cand=tanh(Y2+b_ic+dic + r*(Y3+drc))
__global__ __launch_bounds__(256) void delta_final_kernel(
    const float* __restrict__ carry,
    const float* __restrict__ bias_ir, const float* __restrict__ bias_iu,
    const float* __restrict__ bias_ic,
    const float* __restrict__ lb_ir, const float* __restrict__ lb_rr,
    const float* __restrict__ lb_iu, const float* __restrict__ lb_ru,
    const float* __restrict__ lb_ic, const float* __restrict__ lb_rc,
    const int* __restrict__ starts, const int* __restrict__ order,
    const unsigned short* __restrict__ lowb, const unsigned short* __restrict__ Yall,
    float* __restrict__ out){
  int s = blockIdx.x;
  int c0 = blockIdx.y * 64;
  __shared__ unsigned short Bsm[3 * 64 * 40];    // 3 stacked [col 0..63][k0..31], stride 40
  int t = threadIdx.x;
  const float* lbp[6] = {lb_ir, lb_rr, lb_iu, lb_ru, lb_ic, lb_rc};
  #pragma unroll
  for (int j = 0; j < 6; j++){
    const float* lb = lbp[j] + (size_t)s * R_ * F_;
    unsigned short* Bj = &Bsm[(j >> 1)*2560 + (j & 1)*16];
    int r = t >> 4, c4 = (t & 15) * 4;           // 256 float4 = 16r x 16 col-groups
    float4 v = *(const float4*)&lb[(size_t)r*F_ + c0 + c4];
    Bj[(c4+0)*40 + r] = f2b(v.x);
    Bj[(c4+1)*40 + r] = f2b(v.y);
    Bj[(c4+2)*40 + r] = f2b(v.z);
    Bj[(c4+3)*40 + r] = f2b(v.w);
  }
  __syncthreads();
  int start = starts[s], cnt = starts[s+1] - start;
  if (cnt == 0) return;
  int lane = t & 63, wave = t >> 6;
  int l15 = lane & 15, kq = (lane >> 4) * 8;   // 0,8,16,24
  int ntiles = (cnt + 15) >> 4;
  const unsigned short* Y0 = Yall + 0*(size_t)B_*F_;
  const unsigned short* Y1 = Yall + 1*(size_t)B_*F_;
  const unsigned short* Y2 = Yall + 2*(size_t)B_*F_;
  const unsigned short* Y3 = Yall + 3*(size_t)B_*F_;
  int k8 = kq & 15; bool hi = (kq >= 16);
  // work items: (m-tile, cf-half) pairs; 4 cf slots of 16 cols -> halves of 2
  for (int pt = wave; pt < ntiles*2; pt += 4){
    int mt = pt >> 1, cf0 = (pt & 1) * 2;
    int m = mt*16 + l15; if (m >= cnt) m = cnt - 1;
    int e = order[start + m];
    s16x8 a_r, a_u, a_c1 = {}, a_c2 = {};
    a_r = *(const s16x8*)&lowb[((size_t)(hi ? 3 : 0)*B_ + e)*R_ + k8];
    a_u = *(const s16x8*)&lowb[((size_t)(hi ? 4 : 1)*B_ + e)*R_ + k8];
    if (!hi) a_c1 = *(const s16x8*)&lowb[((size_t)2*B_ + e)*R_ + k8];
    else     a_c2 = *(const s16x8*)&lowb[((size_t)5*B_ + e)*R_ + k8];
    int rowb = (lane >> 4) * 4;
    int erow[4]; bool wok[4];
    #pragma unroll
    for (int i = 0; i < 4; i++){
      int mm = mt*16 + rowb + i;
      wok[i] = (mm < cnt);
      erow[i] = order[start + (wok[i] ? mm : cnt - 1)];
    }
    #pragma unroll
    for (int cf = cf0; cf < cf0 + 2; cf++){
      int col = cf*16 + l15;
      s16x8 b_r = *(const s16x8*)&Bsm[0*2560 + col*40 + kq];
      s16x8 b_u = *(const s16x8*)&Bsm[1*2560 + col*40 + kq];
      s16x8 b_c = *(const s16x8*)&Bsm[2*2560 + col*40 + kq];
      f32x4 zero = {};
      f32x4 dr  = __builtin_amdgcn_mfma_f32_16x16x32_bf16(a_r,  b_r, zero, 0, 0, 0);
      f32x4 du  = __builtin_amdgcn_mfma_f32_16x16x32_bf16(a_u,  b_u, zero, 0, 0, 0);
      f32x4 dic = __builtin_amdgcn_mfma_f32_16x16x32_bf16(a_c1, b_c, zero, 0, 0, 0);
      f32x4 drc = __builtin_amdgcn_mfma_f32_16x16x32_bf16(a_c2, b_c, zero, 0, 0, 0);
      int oc = c0 + col;
      float br = bias_ir[oc], bu = bias_iu[oc], bc = bias_ic[oc];
      #pragma unroll
      for (int i = 0; i < 4; i++){
        if (wok[i]){
          size_t idx = (size_t)erow[i]*F_ + oc;
          float zr  = b2f(Y0[idx]) + br + dr[i];
          float zu  = b2f(Y1[idx]) + bu + du[i];
          float zic = b2f(Y2[idx]) + bc + dic[i];
          float zrc = b2f(Y3[idx]) + drc[i];
          float cv  = carry[idx];
          float rr = 1.f/(1.f+__expf(-zr));
          float uu = 1.f/(1.f+__expf(-zu));
          float a = zic + rr*zrc;
          float ee = __expf(-2.f*fabsf(a));
          float cand = copysignf((1.f-ee)/(1.f+ee), a);
          out[idx] = (1.f-uu)*cand + uu*cv;
        }
      }
    }
  }
}

extern "C" void kernel_launch(void* const* d_in, const int* in_sizes, int n_in,
                              void* d_out, int out_size, void* d_ws, size_t ws_size,
                              hipStream_t stream){
  const float* carry   = (const float*)d_in[0];
  const float* x       = (const float*)d_in[1];
  const int*   ids     = (const int*)d_in[2];
  const float* w_ir    = (const float*)d_in[3];
  const float* bias_ir = (const float*)d_in[4];
  const float* la_ir   = (const float*)d_in[5];
  const float* lb_ir   = (const float*)d_in[6];
  const float* w_iu    = (const float*)d_in[7];
  const float* bias_iu = (const float*)d_in[8];
  const float* la_iu   = (const float*)d_in[9];
  const float* lb_iu   = (const float*)d_in[10];
  const float* w_ic    = (const float*)d_in[11];
  const float* bias_ic = (const float*)d_in[12];
  const float* la_ic   = (const float*)d_in[13];
  const float* lb_ic   = (const float*)d_in[14];
  const float* w_rr    = (const float*)d_in[15];
  const float* la_rr   = (const float*)d_in[16];
  const float* lb_rr   = (const float*)d_in[17];
  const float* w_ru    = (const float*)d_in[18];
  const float* la_ru   = (const float*)d_in[19];
  const float* lb_ru   = (const float*)d_in[20];
  const float* w_rc    = (const float*)d_in[21];
  const float* la_rc   = (const float*)d_in[22];
  const float* lb_rc   = (const float*)d_in[23];

  char* ws = (char*)d_ws;
  unsigned short* XC     = (unsigned short*)(ws + 0);          // 8 MiB
  unsigned short* Wt_all = (unsigned short*)(ws + 8388608);    // 12 MiB
  unsigned short* Yall   = (unsigned short*)(ws + 20971520);   // 16 MiB (4 x 4 MiB bf16)
  unsigned short* lowb   = (unsigned short*)(ws + 37748736);   // 384 KiB bf16
  int* starts = (int*)(ws + 38141952);
  int* order  = (int*)(ws + 38142976);

  prep_kernel<<<dim3(3585), dim3(256), 0, stream>>>(x, carry, XC,
                                                    w_ir, w_rr, w_iu, w_ru, w_ic, w_rc,
                                                    Wt_all, ids, starts, order);
  gemm_low_kernel<<<dim3(896), dim3(256), 0, stream>>>(XC, Wt_all, Yall,
                                                       la_ir, la_iu, la_ic,
                                                       la_rr, la_ru, la_rc,
                                                       starts, order, lowb);
  delta_final_kernel<<<dim3(64, 16), dim3(256), 0, stream>>>(carry, bias_ir, bias_iu, bias_ic,
                                                             lb_ir, lb_rr, lb_iu, lb_ru,
                                                             lb_ic, lb_rc,
                                                             starts, order, lowb, Yall,
                                                             (float*)d_out);
}

// Round 13
// 74.198 us; speedup vs baseline: 1.2109x; 1.0542x over previous
//
#include <hip/hip_runtime.h>
#include <stdint.h>

#define B_  2048
#define D_  1024
#define F_  1024
#define S_  64
#define R_  16

typedef __attribute__((ext_vector_type(8))) short  s16x8;
typedef __attribute__((ext_vector_type(4))) unsigned short u16x4;
typedef __attribute__((ext_vector_type(8))) unsigned short u16x8;
typedef __attribute__((ext_vector_type(4))) float  f32x4;

__device__ __forceinline__ unsigned short f2b(float f){
  unsigned u = __float_as_uint(f);
  u = u + 0x7fffu + ((u >> 16) & 1u);   // RNE to bf16
  return (unsigned short)(u >> 16);
}
__device__ __forceinline__ float b2f(unsigned short s){
  return __uint_as_float(((unsigned)s) << 16);
}

__device__ __forceinline__ void gload16(const void* g, void* l){
  __builtin_amdgcn_global_load_lds((const __attribute__((address_space(1))) unsigned int*)g,
                                   (__attribute__((address_space(3))) unsigned int*)l, 16, 0, 0);
}

// Wt_all element offsets: W0t(ir+rr,K2048)=0, W1t(iu+ru,K2048)=2M, W2t(ic,K1024)=4M, W3t(rc)=5M
#define W0OFF 0
#define W1OFF 2097152
#define W2OFF 4194304
#define W3OFF 5242880

// low g order: 0=ir 1=iu 2=ic 3=rr 4=ru 5=rc

// ---------------- kernel 1: fused prep = cast_xc | wcast | bucket (block-partitioned) -----
__global__ __launch_bounds__(256) void prep_kernel(
    const float* __restrict__ x, const float* __restrict__ carry,
    unsigned short* __restrict__ XC,
    const float* __restrict__ w_ir, const float* __restrict__ w_rr,
    const float* __restrict__ w_iu, const float* __restrict__ w_ru,
    const float* __restrict__ w_ic, const float* __restrict__ w_rc,
    unsigned short* __restrict__ Wt_all,
    const int* __restrict__ ids, int* __restrict__ starts, int* __restrict__ order){
  int bx = blockIdx.x;
  int t = threadIdx.x;
  if (bx < 2048){
    int i = bx * 256 + t;
    int b = i >> 8;
    int j = (i & 255) * 4;
    float4 xv = *(const float4*)&x[(size_t)b*D_ + j];
    float4 cv = *(const float4*)&carry[(size_t)b*F_ + j];
    u16x4 xs, cs;
    xs[0]=f2b(xv.x); xs[1]=f2b(xv.y); xs[2]=f2b(xv.z); xs[3]=f2b(xv.w);
    cs[0]=f2b(cv.x); cs[1]=f2b(cv.y); cs[2]=f2b(cv.z); cs[3]=f2b(cv.w);
    *(u16x4*)&XC[(size_t)b*2048 + j]        = xs;
    *(u16x4*)&XC[(size_t)b*2048 + 1024 + j] = cs;
    return;
  }
  if (bx < 3584){
    int wb = bx - 2048;
    int g = wb >> 8, xb = wb & 255;
    const float* W; unsigned short* O; int st, ko;
    switch(g){
      case 0:  W=w_ir; O=Wt_all+W0OFF; st=2048; ko=0;    break;
      case 1:  W=w_rr; O=Wt_all+W0OFF; st=2048; ko=1024; break;
      case 2:  W=w_iu; O=Wt_all+W1OFF; st=2048; ko=0;    break;
      case 3:  W=w_ru; O=Wt_all+W1OFF; st=2048; ko=1024; break;
      case 4:  W=w_ic; O=Wt_all+W2OFF; st=1024; ko=0;    break;
      default: W=w_rc; O=Wt_all+W3OFF; st=1024; ko=0;    break;
    }
    __shared__ unsigned short T[64][72];   // row stride 144B (9*16B)
    int n0 = (xb & 15) * 64;
    int k0 = (xb >> 4) * 64;
    int c4 = (t & 15) * 4;
    int kk = t >> 4;
    #pragma unroll
    for (int i = 0; i < 4; i++){
      int k = kk + i*16;
      float4 v = *(const float4*)&W[(size_t)(k0+k)*F_ + n0 + c4];
      T[c4+0][k] = f2b(v.x); T[c4+1][k] = f2b(v.y); T[c4+2][k] = f2b(v.z); T[c4+3][k] = f2b(v.w);
    }
    __syncthreads();
    int n = t >> 2, ch = (t & 3) * 16;
    u16x8 a = *(const u16x8*)&T[n][ch];
    u16x8 b = *(const u16x8*)&T[n][ch+8];
    *(u16x8*)&O[(size_t)(n0+n)*st + ko + k0 + ch]     = a;
    *(u16x8*)&O[(size_t)(n0+n)*st + ko + k0 + ch + 8] = b;
    return;
  }
  // bucket
  __shared__ int cnt[S_]; __shared__ int off[S_+1]; __shared__ int cur[S_];
  if (t < S_) cnt[t] = 0;
  __syncthreads();
  for (int b = t; b < B_; b += 256) atomicAdd(&cnt[ids[b]], 1);
  __syncthreads();
  if (t == 0){ off[0] = 0; for (int s2 = 0; s2 < S_; s2++) off[s2+1] = off[s2] + cnt[s2]; }
  __syncthreads();
  if (t < S_) cur[t] = off[t];
  __syncthreads();
  for (int b = t; b < B_; b += 256){ int p = atomicAdd(&cur[ids[b]], 1); order[p] = b; }
  if (t < S_+1) starts[t] = off[t];
}

// ---------------- kernel 2: GEMM (blocks 0..511, balanced XCD squares) + low (512..895) ---
// gemm: 128^2 tile, 4 waves of 64x64, 2-phase dbuf, k-slot swizzle, bf16 Y;
//       units u0/u1 K=2048 (merged ir+rr / iu+ru), u2/u3 K=1024.
//       XCD mapping: every XCD gets 16 tiles of EVERY unit (balanced work), arranged as a
//       4mt x 4nt square -> A-panel 2MB + B-panel 2MB = one 4MB XCD L2.
// low: one m-tile per wave, k-split 2-chain ILP, bf16 output.
__global__ __launch_bounds__(256, 4) void gemm_low_kernel(
    const unsigned short* __restrict__ XC,
    const unsigned short* __restrict__ Wt_all,
    unsigned short* __restrict__ Yall,
    const float* __restrict__ la_ir, const float* __restrict__ la_iu,
    const float* __restrict__ la_ic, const float* __restrict__ la_rr,
    const float* __restrict__ la_ru, const float* __restrict__ la_rc,
    const int* __restrict__ starts, const int* __restrict__ order,
    unsigned short* __restrict__ lowb){
  __shared__ __align__(16) unsigned short smem[16512];   // 33 KB overlay (low LA is max)
  int t = threadIdx.x;
  int bx = blockIdx.x;

  if (bx >= 512){
    // ---- low path ----
    int lb = bx - 512;
    int s = lb & 63, g = lb >> 6;
    const float* la;
    switch(g){ case 0: la=la_ir; break; case 1: la=la_iu; break; case 2: la=la_ic; break;
               case 3: la=la_rr; break; case 4: la=la_ru; break; default: la=la_rc; break; }
    int kofs = (g < 3) ? 0 : 1024;
    la += (size_t)s * D_ * R_;
    unsigned short* LA = smem;             // [r][d] 16 x 1032 (pad 8)
    for (int i4 = t; i4 < D_*R_/4; i4 += 256){
      float4 v = *(const float4*)&la[i4*4];
      int d = i4 >> 2, r0 = (i4 & 3) * 4;
      LA[(r0+0)*1032 + d] = f2b(v.x);
      LA[(r0+1)*1032 + d] = f2b(v.y);
      LA[(r0+2)*1032 + d] = f2b(v.z);
      LA[(r0+3)*1032 + d] = f2b(v.w);
    }
    __syncthreads();
    int start = starts[s], cnt = starts[s+1] - start;
    if (cnt == 0) return;
    int lane = t & 63, wave = t >> 6;
    int l15 = lane & 15, kq = (lane >> 4) * 8;
    int ntiles = (cnt + 15) >> 4;
    for (int mt = wave; mt < ntiles; mt += 4){
      int m0 = mt*16 + l15; if (m0 >= cnt) m0 = cnt - 1;
      int e0 = order[start + m0];
      const unsigned short* A0 = XC + (size_t)e0*2048 + kofs + kq;
      const unsigned short* Bp = &LA[l15*1032 + kq];
      f32x4 accA = {}, accB = {};
      #pragma unroll 4
      for (int kt = 0; kt < 512; kt += 32){
        s16x8 a0 = *(const s16x8*)(A0 + kt);
        s16x8 b0 = *(const s16x8*)(Bp + kt);
        s16x8 a1 = *(const s16x8*)(A0 + 512 + kt);
        s16x8 b1 = *(const s16x8*)(Bp + 512 + kt);
        accA = __builtin_amdgcn_mfma_f32_16x16x32_bf16(a0, b0, accA, 0, 0, 0);
        accB = __builtin_amdgcn_mfma_f32_16x16x32_bf16(a1, b1, accB, 0, 0, 0);
      }
      f32x4 acc = accA + accB;
      int rowb = (lane >> 4) * 4;
      #pragma unroll
      for (int i = 0; i < 4; i++){
        int m = mt*16 + rowb + i;
        if (m < cnt){
          int e = order[start + m];
          lowb[((size_t)g*B_ + e)*R_ + l15] = f2b(acc[i]);
        }
      }
    }
    return;
  }

  // ---- gemm path (128x128, 2-phase), balanced XCD 4x4 tile squares ----
  int u  = bx >> 7;                  // unit 0..3 (every XCD sees every unit)
  int k8x = bx & 7;                  // XCD id (dispatch round-robin)
  int j  = (bx >> 3) & 15;           // within-square index
  int mt = (k8x >> 1) * 4 + (j >> 2);   // 16 mt rows total
  int nt = (k8x & 1) * 4 + (j & 3);     // 8 nt cols total
  int K = (u < 2) ? 2048 : 1024;
  int kofs = (u == 3) ? 1024 : 0;
  const size_t uoffs[4] = {W0OFF, W1OFF, W2OFF, W3OFF};
  const unsigned short* Wt = Wt_all + uoffs[u];
  unsigned short* Y = Yall + (size_t)u * ((size_t)B_ * F_);

  unsigned short (*As)[4096] = (unsigned short(*)[4096])smem;           // [2][128*32]
  unsigned short (*Bs)[4096] = (unsigned short(*)[4096])(smem + 8192);  // [2][128*32]

  int lane = t & 63, wave = t >> 6;
  int row0 = mt * 128, col0 = nt * 128;
  int wrow = (wave >> 1) * 64, wcol = (wave & 1) * 64;

  int arow = t >> 2;
  int achk = ((t & 3) ^ ((t >> 3) & 3)) * 8;   // swizzled source k-slot

  const unsigned short* Ab  = XC + (size_t)(row0 + arow) * 2048 + kofs + achk;
  const unsigned short* Ab2 = Ab + (size_t)64 * 2048;
  const unsigned short* Bb  = Wt + (size_t)(col0 + arow) * K + achk;
  const unsigned short* Bb2 = Bb + (size_t)64 * K;

  int l15 = lane & 15;
  int kof = (((lane >> 4) ^ ((l15 >> 1) & 3)) * 8);   // swizzled read slot
  f32x4 acc[4][4] = {};

  gload16(Ab,  &As[0][t*8]);  gload16(Ab2, &As[0][2048 + t*8]);
  gload16(Bb,  &Bs[0][t*8]);  gload16(Bb2, &Bs[0][2048 + t*8]);
  __syncthreads();

  int cur = 0;
  for (int kt = 32; kt < K; kt += 32){
    int nxt = cur ^ 1;
    gload16(Ab  + kt, &As[nxt][t*8]);  gload16(Ab2 + kt, &As[nxt][2048 + t*8]);
    gload16(Bb  + kt, &Bs[nxt][t*8]);  gload16(Bb2 + kt, &Bs[nxt][2048 + t*8]);
    s16x8 af[4], bfr[4];
    #pragma unroll
    for (int m = 0; m < 4; m++)
      af[m] = *(const s16x8*)&As[cur][(wrow + m*16 + l15)*32 + kof];
    #pragma unroll
    for (int n = 0; n < 4; n++)
      bfr[n] = *(const s16x8*)&Bs[cur][(wcol + n*16 + l15)*32 + kof];
    __builtin_amdgcn_s_setprio(1);
    #pragma unroll
    for (int m = 0; m < 4; m++){
      #pragma unroll
      for (int n = 0; n < 4; n++){
        acc[m][n] = __builtin_amdgcn_mfma_f32_16x16x32_bf16(af[m], bfr[n], acc[m][n], 0, 0, 0);
      }
    }
    __builtin_amdgcn_s_setprio(0);
    __syncthreads();
    cur = nxt;
  }
  {
    s16x8 af[4], bfr[4];
    #pragma unroll
    for (int m = 0; m < 4; m++)
      af[m] = *(const s16x8*)&As[cur][(wrow + m*16 + l15)*32 + kof];
    #pragma unroll
    for (int n = 0; n < 4; n++)
      bfr[n] = *(const s16x8*)&Bs[cur][(wcol + n*16 + l15)*32 + kof];
    #pragma unroll
    for (int m = 0; m < 4; m++){
      #pragma unroll
      for (int n = 0; n < 4; n++){
        acc[m][n] = __builtin_amdgcn_mfma_f32_16x16x32_bf16(af[m], bfr[n], acc[m][n], 0, 0, 0);
      }
    }
  }

  int orow = row0 + wrow + (lane >> 4) * 4;
  int ocol = col0 + wcol + l15;
  #pragma unroll
  for (int m = 0; m < 4; m++){
    #pragma unroll
    for (int n = 0; n < 4; n++){
      #pragma unroll
      for (int i = 0; i < 4; i++){
        Y[(size_t)(orow + m*16 + i) * F_ + ocol + n*16] = f2b(acc[m][n][i]);
      }
    }
  }
}

// ---------------- kernel 3: fused MFMA delta + GRU gates + output (bucketed, bf16) --------
// 64-col tiles, grid (64 ids, 16).
// dr=[low_ir|low_rr]@[lb_ir;lb_rr]; du=[low_iu|low_ru]@[lb_iu;lb_ru]
// dic=[low_ic|0]@[lb_ic;lb_rc];     drc=[0|low_rc]@[lb_ic;lb_rc]
// r=sig(Y0+b_ir+dr), u=sig(Y1+b_iu+du), cand=tanh(Y2+b_ic+dic + r*(Y3+drc))
__global__ __launch_bounds__(256) void delta_final_kernel(
    const float* __restrict__ carry,
    const float* __restrict__ bias_ir, const float* __restrict__ bias_iu,
    const float* __restrict__ bias_ic,
    const float* __restrict__ lb_ir, const float* __restrict__ lb_rr,
    const float* __restrict__ lb_iu, const float* __restrict__ lb_ru,
    const float* __restrict__ lb_ic, const float* __restrict__ lb_rc,
    const int* __restrict__ starts, const int* __restrict__ order,
    const unsigned short* __restrict__ lowb, const unsigned short* __restrict__ Yall,
    float* __restrict__ out){
  int s = blockIdx.x;
  int c0 = blockIdx.y * 64;
  __shared__ unsigned short Bsm[3 * 64 * 40];    // 3 stacked [col 0..63][k0..31], stride 40
  int t = threadIdx.x;
  const float* lbp[6] = {lb_ir, lb_rr, lb_iu, lb_ru, lb_ic, lb_rc};
  #pragma unroll
  for (int j = 0; j < 6; j++){
    const float* lb = lbp[j] + (size_t)s * R_ * F_;
    unsigned short* Bj = &Bsm[(j >> 1)*2560 + (j & 1)*16];
    int r = t >> 4, c4 = (t & 15) * 4;           // 256 float4 = 16r x 16 col-groups
    float4 v = *(const float4*)&lb[(size_t)r*F_ + c0 + c4];
    Bj[(c4+0)*40 + r] = f2b(v.x);
    Bj[(c4+1)*40 + r] = f2b(v.y);
    Bj[(c4+2)*40 + r] = f2b(v.z);
    Bj[(c4+3)*40 + r] = f2b(v.w);
  }
  __syncthreads();
  int start = starts[s], cnt = starts[s+1] - start;
  if (cnt == 0) return;
  int lane = t & 63, wave = t >> 6;
  int l15 = lane & 15, kq = (lane >> 4) * 8;   // 0,8,16,24
  int ntiles = (cnt + 15) >> 4;
  const unsigned short* Y0 = Yall + 0*(size_t)B_*F_;
  const unsigned short* Y1 = Yall + 1*(size_t)B_*F_;
  const unsigned short* Y2 = Yall + 2*(size_t)B_*F_;
  const unsigned short* Y3 = Yall + 3*(size_t)B_*F_;
  int k8 = kq & 15; bool hi = (kq >= 16);
  for (int pt = wave; pt < ntiles*2; pt += 4){
    int mt = pt >> 1, cf0 = (pt & 1) * 2;
    int m = mt*16 + l15; if (m >= cnt) m = cnt - 1;
    int e = order[start + m];
    s16x8 a_r, a_u, a_c1 = {}, a_c2 = {};
    a_r = *(const s16x8*)&lowb[((size_t)(hi ? 3 : 0)*B_ + e)*R_ + k8];
    a_u = *(const s16x8*)&lowb[((size_t)(hi ? 4 : 1)*B_ + e)*R_ + k8];
    if (!hi) a_c1 = *(const s16x8*)&lowb[((size_t)2*B_ + e)*R_ + k8];
    else     a_c2 = *(const s16x8*)&lowb[((size_t)5*B_ + e)*R_ + k8];
    int rowb = (lane >> 4) * 4;
    int erow[4]; bool wok[4];
    #pragma unroll
    for (int i = 0; i < 4; i++){
      int mm = mt*16 + rowb + i;
      wok[i] = (mm < cnt);
      erow[i] = order[start + (wok[i] ? mm : cnt - 1)];
    }
    #pragma unroll
    for (int cf = cf0; cf < cf0 + 2; cf++){
      int col = cf*16 + l15;
      s16x8 b_r = *(const s16x8*)&Bsm[0*2560 + col*40 + kq];
      s16x8 b_u = *(const s16x8*)&Bsm[1*2560 + col*40 + kq];
      s16x8 b_c = *(const s16x8*)&Bsm[2*2560 + col*40 + kq];
      f32x4 zero = {};
      f32x4 dr  = __builtin_amdgcn_mfma_f32_16x16x32_bf16(a_r,  b_r, zero, 0, 0, 0);
      f32x4 du  = __builtin_amdgcn_mfma_f32_16x16x32_bf16(a_u,  b_u, zero, 0, 0, 0);
      f32x4 dic = __builtin_amdgcn_mfma_f32_16x16x32_bf16(a_c1, b_c, zero, 0, 0, 0);
      f32x4 drc = __builtin_amdgcn_mfma_f32_16x16x32_bf16(a_c2, b_c, zero, 0, 0, 0);
      int oc = c0 + col;
      float br = bias_ir[oc], bu = bias_iu[oc], bc = bias_ic[oc];
      #pragma unroll
      for (int i = 0; i < 4; i++){
        if (wok[i]){
          size_t idx = (size_t)erow[i]*F_ + oc;
          float zr  = b2f(Y0[idx]) + br + dr[i];
          float zu  = b2f(Y1[idx]) + bu + du[i];
          float zic = b2f(Y2[idx]) + bc + dic[i];
          float zrc = b2f(Y3[idx]) + drc[i];
          float cv  = carry[idx];
          float rr = 1.f/(1.f+__expf(-zr));
          float uu = 1.f/(1.f+__expf(-zu));
          float a = zic + rr*zrc;
          float ee = __expf(-2.f*fabsf(a));
          float cand = copysignf((1.f-ee)/(1.f+ee), a);
          out[idx] = (1.f-uu)*cand + uu*cv;
        }
      }
    }
  }
}

extern "C" void kernel_launch(void* const* d_in, const int* in_sizes, int n_in,
                              void* d_out, int out_size, void* d_ws, size_t ws_size,
                              hipStream_t stream){
  const float* carry   = (const float*)d_in[0];
  const float* x       = (const float*)d_in[1];
  const int*   ids     = (const int*)d_in[2];
  const float* w_ir    = (const float*)d_in[3];
  const float* bias_ir = (const float*)d_in[4];
  const float* la_ir   = (const float*)d_in[5];
  const float* lb_ir   = (const float*)d_in[6];
  const float* w_iu    = (const float*)d_in[7];
  const float* bias_iu = (const float*)d_in[8];
  const float* la_iu   = (const float*)d_in[9];
  const float* lb_iu   = (const float*)d_in[10];
  const float* w_ic    = (const float*)d_in[11];
  const float* bias_ic = (const float*)d_in[12];
  const float* la_ic   = (const float*)d_in[13];
  const float* lb_ic   = (const float*)d_in[14];
  const float* w_rr    = (const float*)d_in[15];
  const float* la_rr   = (const float*)d_in[16];
  const float* lb_rr   = (const float*)d_in[17];
  const float* w_ru    = (const float*)d_in[18];
  const float* la_ru   = (const float*)d_in[19];
  const float* lb_ru   = (const float*)d_in[20];
  const float* w_rc    = (const float*)d_in[21];
  const float* la_rc   = (const float*)d_in[22];
  const float* lb_rc   = (const float*)d_in[23];

  char* ws = (char*)d_ws;
  unsigned short* XC     = (unsigned short*)(ws + 0);          // 8 MiB
  unsigned short* Wt_all = (unsigned short*)(ws + 8388608);    // 12 MiB
  unsigned short* Yall   = (unsigned short*)(ws + 20971520);   // 16 MiB (4 x 4 MiB bf16)
  unsigned short* lowb   = (unsigned short*)(ws + 37748736);   // 384 KiB bf16
  int* starts = (int*)(ws + 38141952);
  int* order  = (int*)(ws + 38142976);

  prep_kernel<<<dim3(3585), dim3(256), 0, stream>>>(x, carry, XC,
                                                    w_ir, w_rr, w_iu, w_ru, w_ic, w_rc,
                                                    Wt_all, ids, starts, order);
  gemm_low_kernel<<<dim3(896), dim3(256), 0, stream>>>(XC, Wt_all, Yall,
                                                       la_ir, la_iu, la_ic,
                                                       la_rr, la_ru, la_rc,
                                                       starts, order, lowb);
  delta_final_kernel<<<dim3(64, 16), dim3(256), 0, stream>>>(carry, bias_ir, bias_iu, bias_ic,
                                                             lb_ir, lb_rr, lb_iu, lb_ru,
                                                             lb_ic, lb_rc,
                                                             starts, order, lowb, Yall,
                                                             (float*)d_out);
}